// Round 1
// baseline (5572.875 us; speedup 1.0000x reference)
//
#include <hip/hip_runtime.h>

#define NN 100000
#define NE 3200000
#define NR 8

// ---------------- shared: per-(dst,relation) edge counts ----------------
__global__ void count_kernel(const int* __restrict__ dst, const int* __restrict__ et,
                             int* __restrict__ cnt) {
    int e = blockIdx.x * blockDim.x + threadIdx.x;
    if (e < NE) atomicAdd(&cnt[dst[e] * NR + et[e]], 1);
}

// ---------------- Tier A ----------------
// Layer 1 scatter: agg[i][r][k] += x[j][k]   (16 atomics/edge)
__global__ void l1_scatter(const float* __restrict__ x, const int* __restrict__ src,
                           const int* __restrict__ dst, const int* __restrict__ et,
                           float* __restrict__ agg) {
    int e = blockIdx.x * blockDim.x + threadIdx.x;
    if (e >= NE) return;
    int j = src[e], i = dst[e], r = et[e];
    const float4* xv = (const float4*)(x + j * 16);
    float4 a = xv[0], b = xv[1], c = xv[2], d = xv[3];
    float* o = agg + (i * NR + r) * 16;
    atomicAdd(o + 0, a.x);  atomicAdd(o + 1, a.y);  atomicAdd(o + 2, a.z);  atomicAdd(o + 3, a.w);
    atomicAdd(o + 4, b.x);  atomicAdd(o + 5, b.y);  atomicAdd(o + 6, b.z);  atomicAdd(o + 7, b.w);
    atomicAdd(o + 8, c.x);  atomicAdd(o + 9, c.y);  atomicAdd(o + 10, c.z); atomicAdd(o + 11, c.w);
    atomicAdd(o + 12, d.x); atomicAdd(o + 13, d.y); atomicAdd(o + 14, d.z); atomicAdd(o + 15, d.w);
}

// Layer 1 dense: h[i][o] = relu( x_i@root1[:,o] + b1[o] + sum_r (agg[i][r]/max(cnt,1)) @ W1[r][:,o] )
// thread t -> node i = t>>5, output o = t&31
__global__ void l1_dense(const float* __restrict__ x, const float* __restrict__ agg,
                         const int* __restrict__ cnt, const float* __restrict__ W1,
                         const float* __restrict__ root1, const float* __restrict__ b1,
                         float* __restrict__ h) {
    __shared__ float sW[NR * 16 * 32];
    __shared__ float sR[16 * 32];
    __shared__ float sB[32];
    for (int t = threadIdx.x; t < NR * 16 * 32; t += blockDim.x) sW[t] = W1[t];
    for (int t = threadIdx.x; t < 16 * 32; t += blockDim.x) sR[t] = root1[t];
    if (threadIdx.x < 32) sB[threadIdx.x] = b1[threadIdx.x];
    __syncthreads();
    int t = blockIdx.x * blockDim.x + threadIdx.x;
    int i = t >> 5, o = t & 31;
    if (i >= NN) return;
    const float* xi = x + i * 16;
    float acc = sB[o];
#pragma unroll
    for (int k = 0; k < 16; k++) acc += xi[k] * sR[k * 32 + o];
#pragma unroll
    for (int r = 0; r < NR; r++) {
        int c = cnt[i * NR + r];
        float recip = 1.0f / (float)(c > 1 ? c : 1);
        const float* a = agg + (i * NR + r) * 16;
        float s = 0.0f;
#pragma unroll
        for (int k = 0; k < 16; k++) s += a[k] * sW[(r * 16 + k) * 32 + o];
        acc += s * recip;
    }
    h[i * 32 + o] = fmaxf(acc, 0.0f);
}

// Layer 2 source projection: p[j][r][o] = h_j @ W2[r][:,o]
// thread t -> j = t>>7, ro = t&127 (r = ro>>4, o = ro&15)
__global__ void l2_proj(const float* __restrict__ h, const float* __restrict__ W2,
                        float* __restrict__ p) {
    __shared__ float sW[NR * 32 * 16];
    for (int t = threadIdx.x; t < NR * 32 * 16; t += blockDim.x) sW[t] = W2[t];
    __syncthreads();
    int t = blockIdx.x * blockDim.x + threadIdx.x;
    int j = t >> 7, ro = t & 127;
    if (j >= NN) return;
    int r = ro >> 4, o = ro & 15;
    const float* hj = h + j * 32;
    float acc = 0.0f;
#pragma unroll
    for (int k = 0; k < 32; k++) acc += hj[k] * sW[(r * 32 + k) * 16 + o];
    p[j * 128 + ro] = acc;
}

// Layer 2 init: out[i][o] = h_i @ root2[:,o] + b2[o]
// thread t -> i = t>>4, o = t&15
__global__ void l2_init(const float* __restrict__ h, const float* __restrict__ root2,
                        const float* __restrict__ b2, float* __restrict__ out) {
    __shared__ float sR[32 * 16];
    __shared__ float sB[16];
    for (int t = threadIdx.x; t < 32 * 16; t += blockDim.x) sR[t] = root2[t];
    if (threadIdx.x < 16) sB[threadIdx.x] = b2[threadIdx.x];
    __syncthreads();
    int t = blockIdx.x * blockDim.x + threadIdx.x;
    int i = t >> 4, o = t & 15;
    if (i >= NN) return;
    const float* hi = h + i * 32;
    float acc = sB[o];
#pragma unroll
    for (int k = 0; k < 32; k++) acc += hi[k] * sR[k * 16 + o];
    out[i * 16 + o] = acc;
}

// Layer 2 scatter: out[i][k] += p[j][r][k] / max(cnt[i][r],1)   (16 atomics/edge)
__global__ void l2_scatter(const float* __restrict__ p, const int* __restrict__ src,
                           const int* __restrict__ dst, const int* __restrict__ et,
                           const int* __restrict__ cnt, float* __restrict__ out) {
    int e = blockIdx.x * blockDim.x + threadIdx.x;
    if (e >= NE) return;
    int j = src[e], i = dst[e], r = et[e];
    int c = cnt[i * NR + r];
    float recip = 1.0f / (float)(c > 1 ? c : 1);
    const float4* pv = (const float4*)(p + (j * NR + r) * 16);
    float4 a = pv[0], b = pv[1], cc = pv[2], d = pv[3];
    float* o = out + i * 16;
    atomicAdd(o + 0, a.x * recip);  atomicAdd(o + 1, a.y * recip);
    atomicAdd(o + 2, a.z * recip);  atomicAdd(o + 3, a.w * recip);
    atomicAdd(o + 4, b.x * recip);  atomicAdd(o + 5, b.y * recip);
    atomicAdd(o + 6, b.z * recip);  atomicAdd(o + 7, b.w * recip);
    atomicAdd(o + 8, cc.x * recip); atomicAdd(o + 9, cc.y * recip);
    atomicAdd(o + 10, cc.z * recip); atomicAdd(o + 11, cc.w * recip);
    atomicAdd(o + 12, d.x * recip); atomicAdd(o + 13, d.y * recip);
    atomicAdd(o + 14, d.z * recip); atomicAdd(o + 15, d.w * recip);
}

// ---------------- Tier B (small workspace fallback, slow but correct) ----------------
__global__ void l1_init_b(const float* __restrict__ x, const float* __restrict__ root1,
                          const float* __restrict__ b1, float* __restrict__ h) {
    __shared__ float sR[16 * 32];
    __shared__ float sB[32];
    for (int t = threadIdx.x; t < 16 * 32; t += blockDim.x) sR[t] = root1[t];
    if (threadIdx.x < 32) sB[threadIdx.x] = b1[threadIdx.x];
    __syncthreads();
    int t = blockIdx.x * blockDim.x + threadIdx.x;
    int i = t >> 5, o = t & 31;
    if (i >= NN) return;
    const float* xi = x + i * 16;
    float acc = sB[o];
#pragma unroll
    for (int k = 0; k < 16; k++) acc += xi[k] * sR[k * 32 + o];
    h[i * 32 + o] = acc;
}

__global__ void l1_edge_b(const float* __restrict__ x, const int* __restrict__ src,
                          const int* __restrict__ dst, const int* __restrict__ et,
                          const int* __restrict__ cnt, const float* __restrict__ W1,
                          float* __restrict__ h) {
    __shared__ float sW[NR * 16 * 32];
    for (int t = threadIdx.x; t < NR * 16 * 32; t += blockDim.x) sW[t] = W1[t];
    __syncthreads();
    int t = blockIdx.x * blockDim.x + threadIdx.x;
    int e = t >> 5, o = t & 31;
    if (e >= NE) return;
    int j = src[e], i = dst[e], r = et[e];
    int c = cnt[i * NR + r];
    float recip = 1.0f / (float)(c > 1 ? c : 1);
    const float* xj = x + j * 16;
    float acc = 0.0f;
#pragma unroll
    for (int k = 0; k < 16; k++) acc += xj[k] * sW[(r * 16 + k) * 32 + o];
    atomicAdd(&h[i * 32 + o], acc * recip);
}

__global__ void relu_b(float* __restrict__ h) {
    int t = blockIdx.x * blockDim.x + threadIdx.x;
    if (t < NN * 32) h[t] = fmaxf(h[t], 0.0f);
}

__global__ void l2_edge_b(const float* __restrict__ h, const int* __restrict__ src,
                          const int* __restrict__ dst, const int* __restrict__ et,
                          const int* __restrict__ cnt, const float* __restrict__ W2,
                          float* __restrict__ out) {
    __shared__ float sW[NR * 32 * 16];
    for (int t = threadIdx.x; t < NR * 32 * 16; t += blockDim.x) sW[t] = W2[t];
    __syncthreads();
    int t = blockIdx.x * blockDim.x + threadIdx.x;
    int e = t >> 4, o = t & 15;
    if (e >= NE) return;
    int j = src[e], i = dst[e], r = et[e];
    int c = cnt[i * NR + r];
    float recip = 1.0f / (float)(c > 1 ? c : 1);
    const float* hj = h + j * 32;
    float acc = 0.0f;
#pragma unroll
    for (int k = 0; k < 32; k++) acc += hj[k] * sW[(r * 32 + k) * 16 + o];
    atomicAdd(&out[i * 16 + o], acc * recip);
}

extern "C" void kernel_launch(void* const* d_in, const int* in_sizes, int n_in,
                              void* d_out, int out_size, void* d_ws, size_t ws_size,
                              hipStream_t stream) {
    const float* x = (const float*)d_in[0];
    const int* ei = (const int*)d_in[1];
    const int* et = (const int*)d_in[2];
    const float* W1 = (const float*)d_in[3];
    const float* root1 = (const float*)d_in[4];
    const float* b1 = (const float*)d_in[5];
    const float* W2 = (const float*)d_in[6];
    const float* root2 = (const float*)d_in[7];
    const float* b2 = (const float*)d_in[8];
    float* out = (float*)d_out;
    const int* src = ei;
    const int* dst = ei + NE;

    char* ws = (char*)d_ws;
    int* cnt = (int*)ws;                       // NN*8 ints      = 3.2 MB
    float* h = (float*)(ws + 3200000);         // NN*32 floats   = 12.8 MB
    float* buf = (float*)(ws + 16000000);      // NN*8*16 floats = 51.2 MB (agg1, then p2)

    const int TPB = 256;
    hipMemsetAsync(cnt, 0, (size_t)NN * NR * sizeof(int), stream);
    count_kernel<<<(NE + TPB - 1) / TPB, TPB, 0, stream>>>(dst, et, cnt);

    if (ws_size >= 67200000ull) {
        // Tier A: aggregate-first layer 1, source-projection layer 2
        hipMemsetAsync(buf, 0, (size_t)NN * NR * 16 * sizeof(float), stream);
        l1_scatter<<<(NE + TPB - 1) / TPB, TPB, 0, stream>>>(x, src, dst, et, buf);
        l1_dense<<<(NN * 32 + TPB - 1) / TPB, TPB, 0, stream>>>(x, buf, cnt, W1, root1, b1, h);
        l2_proj<<<(NN * 128 + TPB - 1) / TPB, TPB, 0, stream>>>(h, W2, buf);
        l2_init<<<(NN * 16 + TPB - 1) / TPB, TPB, 0, stream>>>(h, root2, b2, out);
        l2_scatter<<<(NE + TPB - 1) / TPB, TPB, 0, stream>>>(buf, src, dst, et, cnt, out);
    } else {
        // Tier B: direct per-edge matvec (needs only cnt + h = 16 MB)
        l1_init_b<<<(NN * 32 + TPB - 1) / TPB, TPB, 0, stream>>>(x, root1, b1, h);
        l1_edge_b<<<((NE * 32) + TPB - 1) / TPB, TPB, 0, stream>>>(x, src, dst, et, cnt, W1, h);
        relu_b<<<(NN * 32 + TPB - 1) / TPB, TPB, 0, stream>>>(h);
        l2_init<<<(NN * 16 + TPB - 1) / TPB, TPB, 0, stream>>>(h, root2, b2, out);
        l2_edge_b<<<((NE * 16) + TPB - 1) / TPB, TPB, 0, stream>>>(h, src, dst, et, cnt, W2, out);
    }
}

// Round 2
// 800.009 us; speedup vs baseline: 6.9660x; 6.9660x over previous
//
#include <hip/hip_runtime.h>

#define NN 100000
#define NE 3200000
#define NR 8
#define NK (NN * NR)          // 800000 (node,rel) keys
#define SCAN_TPB 256
#define SCAN_EPB 1024
#define NB ((NK + SCAN_EPB - 1) / SCAN_EPB)   // 782 blocks

// ---------- histogram of (dst,rel) ----------
__global__ void hist_kernel(const int* __restrict__ dst, const int* __restrict__ et,
                            int* __restrict__ cnt) {
    int e = blockIdx.x * blockDim.x + threadIdx.x;
    if (e < NE) atomicAdd(&cnt[dst[e] * NR + et[e]], 1);
}

// ---------- 3-kernel exclusive scan over cnt[NK] -> off[NK] ----------
__global__ void block_sums(const int* __restrict__ cnt, int* __restrict__ bsum) {
    __shared__ int s[SCAN_TPB];
    int base = blockIdx.x * SCAN_EPB;
    int t = threadIdx.x;
    int v = 0;
#pragma unroll
    for (int j = 0; j < 4; j++) {
        int idx = base + t * 4 + j;
        if (idx < NK) v += cnt[idx];
    }
    s[t] = v; __syncthreads();
    for (int o = SCAN_TPB / 2; o > 0; o >>= 1) {
        if (t < o) s[t] += s[t + o];
        __syncthreads();
    }
    if (t == 0) bsum[blockIdx.x] = s[0];
}

__global__ void scan_sums(int* __restrict__ bsum) {  // single block, 1024 threads
    __shared__ int s[1024];
    int t = threadIdx.x;
    int v = (t < NB) ? bsum[t] : 0;
    s[t] = v; __syncthreads();
    for (int o = 1; o < 1024; o <<= 1) {
        int u = (t >= o) ? s[t - o] : 0;
        __syncthreads();
        s[t] += u;
        __syncthreads();
    }
    if (t < NB) bsum[t] = s[t] - v;  // exclusive
}

__global__ void block_scan(const int* __restrict__ cnt, const int* __restrict__ bsum,
                           int* __restrict__ off) {
    __shared__ int s[SCAN_TPB];
    int base = blockIdx.x * SCAN_EPB;
    int t = threadIdx.x;
    int v[4]; int sum = 0;
#pragma unroll
    for (int j = 0; j < 4; j++) {
        int idx = base + t * 4 + j;
        v[j] = (idx < NK) ? cnt[idx] : 0;
        sum += v[j];
    }
    s[t] = sum; __syncthreads();
    int mine = sum;
    for (int o = 1; o < SCAN_TPB; o <<= 1) {
        int u = (t >= o) ? s[t - o] : 0;
        __syncthreads();
        s[t] += u;
        __syncthreads();
    }
    int ex = s[t] - mine + bsum[blockIdx.x];
#pragma unroll
    for (int j = 0; j < 4; j++) {
        int idx = base + t * 4 + j;
        if (idx < NK) { off[idx] = ex; ex += v[j]; }
    }
}

// ---------- counting-sort scatter: sorted_src by key ----------
// fill (passed as cnt, zeroed beforehand) is re-accumulated to the counts.
__global__ void scatter_ids(const int* __restrict__ src, const int* __restrict__ dst,
                            const int* __restrict__ et, const int* __restrict__ off,
                            int* __restrict__ fill, int* __restrict__ ssrc) {
    int e = blockIdx.x * blockDim.x + threadIdx.x;
    if (e >= NE) return;
    int key = dst[e] * NR + et[e];
    int pos = off[key] + atomicAdd(&fill[key], 1);
    ssrc[pos] = src[e];
}

// ---------- Layer 1 fused: gather-mean + root + 8 rel-matmuls + ReLU ----------
// block = 256 threads = 16 nodes x 16 feature-lanes
__global__ __launch_bounds__(256) void l1_fused(
        const float* __restrict__ x, const int* __restrict__ ssrc,
        const int* __restrict__ off, const int* __restrict__ cnt,
        const float* __restrict__ W1, const float* __restrict__ root1,
        const float* __restrict__ b1, float* __restrict__ h) {
    __shared__ float sW[NR * 16 * 32];   // 16 KB
    __shared__ float sR[16 * 32];
    __shared__ float sB[32];
    __shared__ float sAgg[16][NR * 16 + 1];
    for (int t = threadIdx.x; t < NR * 16 * 32; t += 256) sW[t] = W1[t];
    for (int t = threadIdx.x; t < 16 * 32; t += 256) sR[t] = root1[t];
    if (threadIdx.x < 32) sB[threadIdx.x] = b1[threadIdx.x];

    int nl = threadIdx.x >> 4, k = threadIdx.x & 15;
    int i = blockIdx.x * 16 + nl;    // grid = 6250 exactly
#pragma unroll
    for (int r = 0; r < NR; r++) {
        int key = i * NR + r;
        int s0 = off[key], c = cnt[key];
        float acc = 0.0f;
        for (int e = s0; e < s0 + c; e++) {
            int j = ssrc[e];
            acc += x[j * 16 + k];
        }
        float recip = 1.0f / (float)(c > 1 ? c : 1);
        sAgg[nl][r * 16 + k] = acc * recip;
    }
    __syncthreads();
    // 512 outputs (16 nodes x 32), 2 per thread
#pragma unroll
    for (int ph = 0; ph < 2; ph++) {
        int idx = ph * 256 + threadIdx.x;
        int n2 = idx >> 5, o = idx & 31;
        int ii = blockIdx.x * 16 + n2;
        float acc = sB[o];
        const float* xi = x + ii * 16;
#pragma unroll
        for (int kk = 0; kk < 16; kk++) acc += xi[kk] * sR[kk * 32 + o];
#pragma unroll
        for (int r = 0; r < NR; r++)
#pragma unroll
            for (int kk = 0; kk < 16; kk++)
                acc += sAgg[n2][r * 16 + kk] * sW[(r * 16 + kk) * 32 + o];
        h[ii * 32 + o] = fmaxf(acc, 0.0f);
    }
}

// ---------- Layer 2 fused: gather-mean + root2 + 8 rel-matmuls ----------
// block = 256 threads = 8 nodes x 32 feature-lanes
__global__ __launch_bounds__(256) void l2_fused(
        const float* __restrict__ h, const int* __restrict__ ssrc,
        const int* __restrict__ off, const int* __restrict__ cnt,
        const float* __restrict__ W2, const float* __restrict__ root2,
        const float* __restrict__ b2, float* __restrict__ out) {
    __shared__ float sW[NR * 32 * 16];   // 16 KB
    __shared__ float sR[32 * 16];
    __shared__ float sB[16];
    __shared__ float sAgg[8][NR * 32 + 1];
    for (int t = threadIdx.x; t < NR * 32 * 16; t += 256) sW[t] = W2[t];
    for (int t = threadIdx.x; t < 32 * 16; t += 256) sR[t] = root2[t];
    if (threadIdx.x < 16) sB[threadIdx.x] = b2[threadIdx.x];

    int nl = threadIdx.x >> 5, k = threadIdx.x & 31;
    int i = blockIdx.x * 8 + nl;    // grid = 12500 exactly
#pragma unroll
    for (int r = 0; r < NR; r++) {
        int key = i * NR + r;
        int s0 = off[key], c = cnt[key];
        float acc = 0.0f;
        for (int e = s0; e < s0 + c; e++) {
            int j = ssrc[e];
            acc += h[j * 32 + k];
        }
        float recip = 1.0f / (float)(c > 1 ? c : 1);
        sAgg[nl][r * 32 + k] = acc * recip;
    }
    __syncthreads();
    // per node: 16 outputs, k-sum split in two halves across the 32 lanes
    int o = k & 15, half = k >> 4;
    float acc = 0.0f;
    const float* hi = h + i * 32;
#pragma unroll
    for (int kk = 0; kk < 16; kk++) {
        int kf = half * 16 + kk;
        acc += hi[kf] * sR[kf * 16 + o];
    }
#pragma unroll
    for (int r = 0; r < NR; r++)
#pragma unroll
        for (int kk = 0; kk < 16; kk++) {
            int kf = half * 16 + kk;
            acc += sAgg[nl][r * 32 + kf] * sW[(r * 32 + kf) * 16 + o];
        }
    float other = __shfl_xor(acc, 16);
    float tot = acc + other;
    if (half == 0) out[i * 16 + o] = tot + sB[o];
}

extern "C" void kernel_launch(void* const* d_in, const int* in_sizes, int n_in,
                              void* d_out, int out_size, void* d_ws, size_t ws_size,
                              hipStream_t stream) {
    const float* x = (const float*)d_in[0];
    const int* ei = (const int*)d_in[1];
    const int* et = (const int*)d_in[2];
    const float* W1 = (const float*)d_in[3];
    const float* root1 = (const float*)d_in[4];
    const float* b1 = (const float*)d_in[5];
    const float* W2 = (const float*)d_in[6];
    const float* root2 = (const float*)d_in[7];
    const float* b2 = (const float*)d_in[8];
    float* out = (float*)d_out;
    const int* src = ei;
    const int* dst = ei + NE;

    char* ws = (char*)d_ws;
    int* cnt   = (int*)(ws + 0);           // 3.2 MB
    int* off   = (int*)(ws + 3200000);     // 3.2 MB
    int* bsum  = (int*)(ws + 6400000);     // ~3.2 KB
    int* ssrc  = (int*)(ws + 6406400);     // 12.8 MB
    float* h   = (float*)(ws + 19206400);  // 12.8 MB  (total ~32 MB)

    const int TPB = 256;
    // build counts
    hipMemsetAsync(cnt, 0, (size_t)NK * sizeof(int), stream);
    hist_kernel<<<(NE + TPB - 1) / TPB, TPB, 0, stream>>>(dst, et, cnt);
    // exclusive scan -> off
    block_sums<<<NB, SCAN_TPB, 0, stream>>>(cnt, bsum);
    scan_sums<<<1, 1024, 0, stream>>>(bsum);
    block_scan<<<NB, SCAN_TPB, 0, stream>>>(cnt, bsum, off);
    // counting-sort sources by (dst,rel); cnt reused as fill and restored to counts
    hipMemsetAsync(cnt, 0, (size_t)NK * sizeof(int), stream);
    scatter_ids<<<(NE + TPB - 1) / TPB, TPB, 0, stream>>>(src, dst, et, off, cnt, ssrc);
    // fused layers
    l1_fused<<<NN / 16, 256, 0, stream>>>(x, ssrc, off, cnt, W1, root1, b1, h);
    l2_fused<<<NN / 8, 256, 0, stream>>>(h, ssrc, off, cnt, W2, root2, b2, out);
}

// Round 3
// 516.901 us; speedup vs baseline: 10.7813x; 1.5477x over previous
//
#include <hip/hip_runtime.h>

#define NN 100000
#define NE 3200000
#define NR 8
#define NK (NN * NR)          // 800000 (node,rel) keys
#define SCAN_TPB 256
#define SCAN_EPB 1024
#define NB ((NK + SCAN_EPB - 1) / SCAN_EPB)   // 782 blocks

// ---------- histogram of (dst,rel) ----------
__global__ void hist_kernel(const int* __restrict__ dst, const int* __restrict__ et,
                            int* __restrict__ cnt) {
    int e = blockIdx.x * blockDim.x + threadIdx.x;
    if (e < NE) atomicAdd(&cnt[dst[e] * NR + et[e]], 1);
}

// ---------- 3-kernel exclusive scan over cnt[NK] -> off[NK] ----------
__global__ void block_sums(const int* __restrict__ cnt, int* __restrict__ bsum) {
    __shared__ int s[SCAN_TPB];
    int base = blockIdx.x * SCAN_EPB;
    int t = threadIdx.x;
    int v = 0;
#pragma unroll
    for (int j = 0; j < 4; j++) {
        int idx = base + t * 4 + j;
        if (idx < NK) v += cnt[idx];
    }
    s[t] = v; __syncthreads();
    for (int o = SCAN_TPB / 2; o > 0; o >>= 1) {
        if (t < o) s[t] += s[t + o];
        __syncthreads();
    }
    if (t == 0) bsum[blockIdx.x] = s[0];
}

__global__ void scan_sums(int* __restrict__ bsum) {  // single block, 1024 threads
    __shared__ int s[1024];
    int t = threadIdx.x;
    int v = (t < NB) ? bsum[t] : 0;
    s[t] = v; __syncthreads();
    for (int o = 1; o < 1024; o <<= 1) {
        int u = (t >= o) ? s[t - o] : 0;
        __syncthreads();
        s[t] += u;
        __syncthreads();
    }
    if (t < NB) bsum[t] = s[t] - v;  // exclusive
}

__global__ void block_scan(const int* __restrict__ cnt, const int* __restrict__ bsum,
                           int* __restrict__ off) {
    __shared__ int s[SCAN_TPB];
    int base = blockIdx.x * SCAN_EPB;
    int t = threadIdx.x;
    int v[4]; int sum = 0;
#pragma unroll
    for (int j = 0; j < 4; j++) {
        int idx = base + t * 4 + j;
        v[j] = (idx < NK) ? cnt[idx] : 0;
        sum += v[j];
    }
    s[t] = sum; __syncthreads();
    int mine = sum;
    for (int o = 1; o < SCAN_TPB; o <<= 1) {
        int u = (t >= o) ? s[t - o] : 0;
        __syncthreads();
        s[t] += u;
        __syncthreads();
    }
    int ex = s[t] - mine + bsum[blockIdx.x];
#pragma unroll
    for (int j = 0; j < 4; j++) {
        int idx = base + t * 4 + j;
        if (idx < NK) { off[idx] = ex; ex += v[j]; }
    }
}

// ---------- counting-sort scatter: sorted_src by key ----------
__global__ void scatter_ids(const int* __restrict__ src, const int* __restrict__ dst,
                            const int* __restrict__ et, const int* __restrict__ off,
                            int* __restrict__ fill, int* __restrict__ ssrc) {
    int e = blockIdx.x * blockDim.x + threadIdx.x;
    if (e >= NE) return;
    int key = dst[e] * NR + et[e];
    int pos = off[key] + atomicAdd(&fill[key], 1);
    ssrc[pos] = src[e];
}

// ---------- Layer 1 fused: gather-mean + root + 8 rel-matmuls + ReLU ----------
// block = 256 threads = 16 nodes x 16 feature-lanes
__global__ __launch_bounds__(256, 8) void l1_fused(
        const float* __restrict__ x, const int* __restrict__ ssrc,
        const int* __restrict__ off, const int* __restrict__ cnt,
        const float* __restrict__ W1, const float* __restrict__ root1,
        const float* __restrict__ b1, float* __restrict__ h) {
    __shared__ float sAgg[16][NR * 16 + 8];   // stride 136 words -> <=2-way banks
    __shared__ int   sOff[16 * NR];
    __shared__ int   sCnt[16 * NR];
    __shared__ float sRecip[16 * NR];
    {
        int t = threadIdx.x;
        if (t < 16 * NR) {
            int key = blockIdx.x * 16 * NR + t;
            int o0 = off[key], c = cnt[key];
            sOff[t] = o0; sCnt[t] = c;
            sRecip[t] = 1.0f / (float)(c > 1 ? c : 1);
        }
    }
    __syncthreads();

    int nl = threadIdx.x >> 4, k = threadIdx.x & 15;
    int kb = nl * NR;
#pragma unroll
    for (int r = 0; r < NR; r++) {
        int s0 = sOff[kb + r];
        int c  = sCnt[kb + r];
        float acc = 0.0f;
        for (int e0 = 0; e0 < c; e0 += 4) {
            int i0 = s0 + e0;
            int j0 = ssrc[min(i0 + 0, NE - 1)];
            int j1 = ssrc[min(i0 + 1, NE - 1)];
            int j2 = ssrc[min(i0 + 2, NE - 1)];
            int j3 = ssrc[min(i0 + 3, NE - 1)];
            float v0 = x[j0 * 16 + k];
            float v1 = x[j1 * 16 + k];
            float v2 = x[j2 * 16 + k];
            float v3 = x[j3 * 16 + k];
            acc += (e0 + 0 < c ? v0 : 0.0f);
            acc += (e0 + 1 < c ? v1 : 0.0f);
            acc += (e0 + 2 < c ? v2 : 0.0f);
            acc += (e0 + 3 < c ? v3 : 0.0f);
        }
        sAgg[nl][r * 16 + k] = acc * sRecip[kb + r];
    }
    __syncthreads();
    // 512 outputs (16 nodes x 32), 2 per thread; W1/root1/b1 read via L1 (hot)
#pragma unroll
    for (int ph = 0; ph < 2; ph++) {
        int idx = ph * 256 + threadIdx.x;
        int n2 = idx >> 5, o = idx & 31;
        int ii = blockIdx.x * 16 + n2;
        float acc = b1[o];
        const float* xi = x + ii * 16;
#pragma unroll
        for (int kk = 0; kk < 16; kk++) acc += xi[kk] * root1[kk * 32 + o];
#pragma unroll
        for (int r = 0; r < NR; r++)
#pragma unroll
            for (int kk = 0; kk < 16; kk++)
                acc += sAgg[n2][r * 16 + kk] * W1[(r * 16 + kk) * 32 + o];
        h[ii * 32 + o] = fmaxf(acc, 0.0f);
    }
}

// ---------- Layer 2 fused: gather-mean + root2 + 8 rel-matmuls ----------
// block = 256 threads = 8 nodes x 32 feature-lanes
__global__ __launch_bounds__(256, 8) void l2_fused(
        const float* __restrict__ h, const int* __restrict__ ssrc,
        const int* __restrict__ off, const int* __restrict__ cnt,
        const float* __restrict__ W2, const float* __restrict__ root2,
        const float* __restrict__ b2, float* __restrict__ out) {
    __shared__ float sAgg[8][NR * 32 + 1];    // stride 257 words -> 2-way banks
    __shared__ int   sOff[8 * NR];
    __shared__ int   sCnt[8 * NR];
    __shared__ float sRecip[8 * NR];
    {
        int t = threadIdx.x;
        if (t < 8 * NR) {
            int key = blockIdx.x * 8 * NR + t;
            int o0 = off[key], c = cnt[key];
            sOff[t] = o0; sCnt[t] = c;
            sRecip[t] = 1.0f / (float)(c > 1 ? c : 1);
        }
    }
    __syncthreads();

    int nl = threadIdx.x >> 5, k = threadIdx.x & 31;
    int i = blockIdx.x * 8 + nl;
    int kb = nl * NR;
#pragma unroll
    for (int r = 0; r < NR; r++) {
        int s0 = sOff[kb + r];
        int c  = sCnt[kb + r];
        float acc = 0.0f;
        for (int e0 = 0; e0 < c; e0 += 4) {
            int i0 = s0 + e0;
            int j0 = ssrc[min(i0 + 0, NE - 1)];
            int j1 = ssrc[min(i0 + 1, NE - 1)];
            int j2 = ssrc[min(i0 + 2, NE - 1)];
            int j3 = ssrc[min(i0 + 3, NE - 1)];
            float v0 = h[j0 * 32 + k];
            float v1 = h[j1 * 32 + k];
            float v2 = h[j2 * 32 + k];
            float v3 = h[j3 * 32 + k];
            acc += (e0 + 0 < c ? v0 : 0.0f);
            acc += (e0 + 1 < c ? v1 : 0.0f);
            acc += (e0 + 2 < c ? v2 : 0.0f);
            acc += (e0 + 3 < c ? v3 : 0.0f);
        }
        sAgg[nl][r * 32 + k] = acc * sRecip[kb + r];
    }
    __syncthreads();
    // per node: 16 outputs, k-sum split across lane halves; W2/root2/b2 via L1
    int o = k & 15, half = k >> 4;
    float acc = 0.0f;
    const float* hi = h + i * 32;
#pragma unroll
    for (int kk = 0; kk < 16; kk++) {
        int kf = half * 16 + kk;
        acc += hi[kf] * root2[kf * 16 + o];
    }
#pragma unroll
    for (int r = 0; r < NR; r++)
#pragma unroll
        for (int kk = 0; kk < 16; kk++) {
            int kf = half * 16 + kk;
            acc += sAgg[nl][r * 32 + kf] * W2[(r * 32 + kf) * 16 + o];
        }
    float tot = acc + __shfl_xor(acc, 16);
    if (half == 0) out[i * 16 + o] = tot + b2[o];
}

extern "C" void kernel_launch(void* const* d_in, const int* in_sizes, int n_in,
                              void* d_out, int out_size, void* d_ws, size_t ws_size,
                              hipStream_t stream) {
    const float* x = (const float*)d_in[0];
    const int* ei = (const int*)d_in[1];
    const int* et = (const int*)d_in[2];
    const float* W1 = (const float*)d_in[3];
    const float* root1 = (const float*)d_in[4];
    const float* b1 = (const float*)d_in[5];
    const float* W2 = (const float*)d_in[6];
    const float* root2 = (const float*)d_in[7];
    const float* b2 = (const float*)d_in[8];
    float* out = (float*)d_out;
    const int* src = ei;
    const int* dst = ei + NE;

    char* ws = (char*)d_ws;
    int* cnt   = (int*)(ws + 0);           // 3.2 MB
    int* off   = (int*)(ws + 3200000);     // 3.2 MB
    int* bsum  = (int*)(ws + 6400000);     // ~3.2 KB
    int* ssrc  = (int*)(ws + 6406400);     // 12.8 MB
    float* h   = (float*)(ws + 19206400);  // 12.8 MB  (total ~32 MB)

    const int TPB = 256;
    // build counts
    hipMemsetAsync(cnt, 0, (size_t)NK * sizeof(int), stream);
    hist_kernel<<<(NE + TPB - 1) / TPB, TPB, 0, stream>>>(dst, et, cnt);
    // exclusive scan -> off
    block_sums<<<NB, SCAN_TPB, 0, stream>>>(cnt, bsum);
    scan_sums<<<1, 1024, 0, stream>>>(bsum);
    block_scan<<<NB, SCAN_TPB, 0, stream>>>(cnt, bsum, off);
    // counting-sort sources by (dst,rel); cnt reused as fill and restored to counts
    hipMemsetAsync(cnt, 0, (size_t)NK * sizeof(int), stream);
    scatter_ids<<<(NE + TPB - 1) / TPB, TPB, 0, stream>>>(src, dst, et, off, cnt, ssrc);
    // fused layers
    l1_fused<<<NN / 16, 256, 0, stream>>>(x, ssrc, off, cnt, W1, root1, b1, h);
    l2_fused<<<NN / 8, 256, 0, stream>>>(h, ssrc, off, cnt, W2, root2, b2, out);
}